// Round 14
// baseline (93.841 us; speedup 1.0000x reference)
//
#include <hip/hip_runtime.h>

// LocalSelfAttention2d  B=16,C=256,H=W=64,P=8,HEADS=8,D=32
// Round 14: K1 VALU/scatter diet via MFMA operand-swap transposes.
//  A-frag and B-frag have IDENTICAL register layouts (row/col=l&15, k=(l>>4)*8+v),
//  so mfma(B,A) computes the transposed tile for free:
//   - V-tiles in phase 2: mfma(bf,af) -> D[pix][d] lane=d, regs=4 consecutive pix
//     -> V scatter = 4 packed u64 LDS stores (was 16 scalar u16 + 16 cvt).
//   - PV: mfma(vf,pf) -> O^T lane=q, regs=4 consecutive c
//     -> O write = 4 packed u64 global stores (was 16 scalar u16 + 16 cvt).
//  Also removed the provably-unneeded barrier before P-overlay (each wave
//  reads/writes only its own 32 Q rows -> within-wave hazard only).
// prep/K2 unchanged (both near BW floor).
// MFMA 16x16x32_f16 D-layout (verified): col=l&15, row=(l>>4)*4+r;
//  contraction D[i][j] = sum_k A[i][k]B[j][k], A lane supplies row i, B lane col j.

typedef _Float16 f16x8 __attribute__((ext_vector_type(8)));
typedef float    f32x4 __attribute__((ext_vector_type(4)));
typedef unsigned short u16;
typedef unsigned int   u32;
typedef unsigned long long u64;

#define SCALE 0.17677669529663687f  // 1/sqrt(32)
#define QK_S  40    // Q/K [64 pix][40 d]
#define VT_S  72    // V  [32 d][72 k]
#define PB_S  40    // P (overlays Q) [64 q][40 k]
#define LT_S  264   // transpose staging stride
#define XW_S  264   // x-window LDS stride (528B rows, 2-way banks)
#define OT_S  264   // K2 row-tile stride

__device__ __forceinline__ u16 f2hu(float f) {
    _Float16 h = (_Float16)f; return __builtin_bit_cast(u16, h);
}
__device__ __forceinline__ u64 pack4h(f32x4 v) {
    u32 lo = __builtin_bit_cast(u32, __builtin_amdgcn_cvt_pkrtz(v[0], v[1]));
    u32 hi = __builtin_bit_cast(u32, __builtin_amdgcn_cvt_pkrtz(v[2], v[3]));
    return ((u64)hi << 32) | (u64)lo;
}

// ---------------- prep: fused weight-convert + x transpose ----------------
__global__ __launch_bounds__(512)
void prep(const float* __restrict__ x, const float* __restrict__ wp,
          const float* __restrict__ wo, u16* __restrict__ xtw,
          u16* __restrict__ w16k, u16* __restrict__ wo16k)
{
    __shared__ u16 Lt[64 * LT_S];
    const int bid = blockIdx.x;
    const int tid = threadIdx.x;
    if (bid < 1024) {
        const int y = bid & 63, b = bid >> 6;
        const int yq = y >> 3, py = y & 7;
        const float* xb = x + ((size_t)b * 256) * 4096 + y * 64;
        #pragma unroll
        for (int i = 0; i < 8; ++i) {
            int idx = tid + i * 512;            // 4096 float4s
            int c = idx >> 4, w4 = (idx & 15) << 2;
            float4 v = *(const float4*)(xb + (size_t)c * 4096 + w4);
            float vv[4] = {v.x, v.y, v.z, v.w};
            #pragma unroll
            for (int j = 0; j < 4; ++j) {
                int w = w4 + j;
                Lt[w * LT_S + (c ^ (((w >> 2) & 7) << 3))] = f2hu(vv[j]);
            }
        }
        __syncthreads();
        u16* dst = xtw + (size_t)(b * 64 + yq * 8) * 16384;   // window-row base
        #pragma unroll
        for (int i = 0; i < 4; ++i) {
            int idx = tid + i * 512;            // 2048 f16x8 stores
            int w = idx >> 5, c8 = (idx & 31) << 3;
            f16x8 v = *(const f16x8*)(&Lt[w * LT_S + (c8 ^ (((w >> 2) & 7) << 3))]);
            *(f16x8*)(dst + (w >> 3) * 16384 + (py * 8 + (w & 7)) * 256 + c8) = v;
        }
    } else {
        int idx = (bid - 1024) * 512 + tid;     // 0..262143
        if (idx < 196608) {
            int hq = idx / 98304, o = idx - hq * 98304;
            int kt = o / 12288, o2 = o - kt * 12288;
            int lr = o2 >> 5, cc = o2 & 31;
            int s = lr >> 7, hh = (lr >> 5) & 3, d = lr & 31;
            w16k[idx] = f2hu(wp[(size_t)(s * 256 + (hq * 4 + hh) * 32 + d) * 256 + kt * 32 + cc]);
        } else {
            int j = idx - 196608;               // 0..65535
            int kt = j >> 13, o2 = j & 8191;
            int row = o2 >> 5, cc = o2 & 31;
            wo16k[j] = f2hu(wo[(size_t)row * 256 + kt * 32 + cc]);
        }
    }
}

// ---------------- K1: QKV projection + windowed attention ----------------
__global__ __launch_bounds__(512, 4)
void lsa_qkv_attn_xt(const u16* __restrict__ xtw, const u16* __restrict__ w16k,
                     const float* __restrict__ position, u16* __restrict__ Ows)
{
    // U overlay: phase 1-2: XwL[64][264] = 16896 u16
    //            phase 3-4: Qb 10240 | Kb 10240 | Vt 9216 = 29696 u16
    __shared__ u16 U[29696];        // 59392 B
    __shared__ float POSL[1024];    // 4096 B: this block's hq-half (4 heads)
    u16* XwL = U;                   // [64][264]
    u16* Qb  = U;                   // [4][64][40]
    u16* Kb  = U + 10240;
    u16* Vt  = U + 20480;           // [4][32][72]

    const int tid = threadIdx.x;
    const int hq = blockIdx.x & 1, win = blockIdx.x >> 1, b = blockIdx.y;
    const int w = tid >> 6, m = tid & 15, lg = (tid >> 4) & 3;

    // stage position half + x window (shared operands)
    *(float2*)(&POSL[tid * 2]) = *(const float2*)(position + hq * 1024 + tid * 2);
    {
        const u16* xwin = xtw + (size_t)(b * 64 + win) * 16384;
        #pragma unroll
        for (int i = 0; i < 4; ++i) {
            int g = tid + i * 512;              // 2048 16B-chunks
            *(f16x8*)(XwL + (g >> 5) * XW_S + (g & 31) * 8) = *(const f16x8*)(xwin + g * 8);
        }
    }
    __syncthreads();

    // ---- phase 2: QKV GEMM; A (weights) direct global, B (window) from LDS.
    //      V-tiles (isv==2) use swapped operands -> transposed D (pix in regs).
    f32x4 acc[3][4];
    int isv[3], hhv[3], d0v[3], lr0v[3];
    {
        const f32x4 z = {0.f, 0.f, 0.f, 0.f};
        #pragma unroll
        for (int i = 0; i < 3; ++i) {
            #pragma unroll
            for (int nt = 0; nt < 4; ++nt) acc[i][nt] = z;
            int lr0 = (3 * w + i) * 16;           // local row: s*128 + hh*32 + d
            lr0v[i] = lr0;
            isv[i] = lr0 >> 7; hhv[i] = (lr0 >> 5) & 3; d0v[i] = lr0 & 31;
        }
        const u16* wbase = w16k + (size_t)hq * 98304;
        #pragma unroll
        for (int kt = 0; kt < 8; ++kt) {
            f16x8 af[3], bf[4];
            #pragma unroll
            for (int i = 0; i < 3; ++i)
                af[i] = *(const f16x8*)(wbase + kt * 12288 + (lr0v[i] + m) * 32 + lg * 8);
            #pragma unroll
            for (int nt = 0; nt < 4; ++nt)
                bf[nt] = *(const f16x8*)(XwL + (nt * 16 + m) * XW_S + kt * 32 + lg * 8);
            #pragma unroll
            for (int i = 0; i < 3; ++i) {
                if (isv[i] == 2) {   // V: D[pix][d] (lane=d, regs=pix)
                    #pragma unroll
                    for (int nt = 0; nt < 4; ++nt)
                        acc[i][nt] = __builtin_amdgcn_mfma_f32_16x16x32_f16(bf[nt], af[i], acc[i][nt], 0, 0, 0);
                } else {             // Q/K: D[d][pix] (lane=pix, regs=d)
                    #pragma unroll
                    for (int nt = 0; nt < 4; ++nt)
                        acc[i][nt] = __builtin_amdgcn_mfma_f32_16x16x32_f16(af[i], bf[nt], acc[i][nt], 0, 0, 0);
                }
            }
        }
    }
    __syncthreads();   // XwL reads done before Q/K/V overlay U

    // ---- phase 3: scatter Q/K/V to per-head LDS (all packed u64 now)
    {
        #pragma unroll
        for (int i = 0; i < 3; ++i) {
            int i_s = isv[i], hh = hhv[i], d0 = d0v[i];
            #pragma unroll
            for (int nt = 0; nt < 4; ++nt) {
                if (i_s < 2) {
                    int pix = nt * 16 + m;
                    u16* base = (i_s == 0) ? Qb : Kb;
                    *(u64*)(base + hh * 64 * QK_S + pix * QK_S + d0 + lg * 4) = pack4h(acc[i][nt]);
                } else {
                    // lane m = d-within-tile; regs = 4 consecutive pix
                    *(u64*)(Vt + hh * 32 * VT_S + (d0 + m) * VT_S + nt * 16 + lg * 4) = pack4h(acc[i][nt]);
                }
            }
        }
    }
    __syncthreads();

    // ---- phase 4: attention; 2 waves per head
    {
        const int hh = w >> 1, qh = w & 1;
        const u16* Qh = Qb + hh * 64 * QK_S;
        const u16* Kh = Kb + hh * 64 * QK_S;
        const u16* Vh = Vt + hh * 32 * VT_S;
        u16* Ph = Qb + hh * 64 * PB_S;          // OVERLAY: P reuses Q region
        const float* posh = &POSL[hh * 256];

        f16x8 kf[4], qf[2];
        #pragma unroll
        for (int kt = 0; kt < 4; ++kt)
            kf[kt] = *(const f16x8*)(Kh + (kt * 16 + m) * QK_S + lg * 8);
        #pragma unroll
        for (int qi = 0; qi < 2; ++qi)
            qf[qi] = *(const f16x8*)(Qh + ((2 * qh + qi) * 16 + m) * QK_S + lg * 8);
        // NOTE: no barrier needed: this wave reads only its own 32 Q rows,
        // which are exactly the rows it overwrites with P below.

        const f32x4 z = {0.f, 0.f, 0.f, 0.f};
        f32x4 st[4][2];
        #pragma unroll
        for (int kt = 0; kt < 4; ++kt)
            #pragma unroll
            for (int qi = 0; qi < 2; ++qi)
                st[kt][qi] = __builtin_amdgcn_mfma_f32_16x16x32_f16(kf[kt], qf[qi], z, 0, 0, 0);
        // lane holds S[q=(2qh+qi)*16+m][k=kt*16+lg*4+r]

        float inv[2];
        #pragma unroll
        for (int qi = 0; qi < 2; ++qi) {
            int q = (2 * qh + qi) * 16 + m, qy = q >> 3, qx = q & 7;
            float mx = -1e30f;
            #pragma unroll
            for (int kt = 0; kt < 4; ++kt)
                #pragma unroll
                for (int r = 0; r < 4; ++r) {
                    int k = kt * 16 + lg * 4 + r, ky = k >> 3, kx = k & 7;
                    float t = st[kt][qi][r] * SCALE + posh[(ky - qy + 8) * 16 + (kx - qx + 8)];
                    st[kt][qi][r] = t;
                    mx = fmaxf(mx, t);
                }
            mx = fmaxf(mx, __shfl_xor(mx, 16));
            mx = fmaxf(mx, __shfl_xor(mx, 32));
            float sum = 0.f;
            #pragma unroll
            for (int kt = 0; kt < 4; ++kt)
                #pragma unroll
                for (int r = 0; r < 4; ++r) {
                    float e = __expf(st[kt][qi][r] - mx);
                    st[kt][qi][r] = e; sum += e;
                }
            sum += __shfl_xor(sum, 16);
            sum += __shfl_xor(sum, 32);
            inv[qi] = 1.f / sum;
        }

        f32x4 ot[2][2];
        ot[0][0] = z; ot[0][1] = z; ot[1][0] = z; ot[1][1] = z;
        #pragma unroll
        for (int ks = 0; ks < 2; ++ks) {
            #pragma unroll
            for (int kh = 0; kh < 2; ++kh) {
                int kt = 2 * ks + kh;
                #pragma unroll
                for (int qi = 0; qi < 2; ++qi) {
                    f32x4 pv = st[kt][qi] * inv[qi];
                    *(u64*)(Ph + ((2 * qh + qi) * 16 + m) * PB_S + kh * 16 + lg * 4) = pack4h(pv);
                }
            }
            f16x8 pf[2], vf[2];
            #pragma unroll
            for (int qi = 0; qi < 2; ++qi)
                pf[qi] = *(const f16x8*)(Ph + ((2 * qh + qi) * 16 + m) * PB_S + lg * 8);
            #pragma unroll
            for (int dt = 0; dt < 2; ++dt)
                vf[dt] = *(const f16x8*)(Vh + (dt * 16 + m) * VT_S + ks * 32 + lg * 8);
            // swapped: D[d][q] -> lane=q, regs=4 consecutive d (O^T in-lane)
            #pragma unroll
            for (int qi = 0; qi < 2; ++qi)
                #pragma unroll
                for (int dt = 0; dt < 2; ++dt)
                    ot[qi][dt] = __builtin_amdgcn_mfma_f32_16x16x32_f16(vf[dt], pf[qi], ot[qi][dt], 0, 0, 0);
        }

        // O -> Ows [bw][pix][c] fp16: lane=q, 4 consecutive c -> packed u64
        const size_t obase = (size_t)(b * 64 + win) * 16384;
        const int head = hq * 4 + hh;
        #pragma unroll
        for (int qi = 0; qi < 2; ++qi) {
            int q = (2 * qh + qi) * 16 + m;
            #pragma unroll
            for (int dt = 0; dt < 2; ++dt) {
                int c0 = head * 32 + dt * 16 + lg * 4;
                *(u64*)(&Ows[obase + q * 256 + c0]) = pack4h(ot[qi][dt]);
            }
        }
    }
}

// -------- K2: out-projection, ROW-major blocks (unchanged R13) --------
__global__ __launch_bounds__(512, 4)
void lsa_outproj_row(const u16* __restrict__ Ows, const u16* __restrict__ wo16k,
                     const float* __restrict__ b_out, float* __restrict__ out)
{
    __shared__ u16 Ot[64 * OT_S];    // 33792 B [64 px][264 c]

    const int tid = threadIdx.x;
    const int y = blockIdx.x, b = blockIdx.y;
    const int yq = y >> 3, py = y & 7;
    const int w = tid >> 6, m = tid & 15, lg = (tid >> 4) & 3;

    {
        const u16* slab = Ows + (size_t)(b * 64 + yq * 8) * 16384 + (py * 8) * 256;
        #pragma unroll
        for (int i = 0; i < 4; ++i) {
            int g = tid + i * 512;              // 2048 16B-chunks
            int wx = g >> 8, gg = g & 255;
            int lx = gg >> 5, c8 = (gg & 31) << 3;
            f16x8 v = *(const f16x8*)(slab + (size_t)wx * 16384 + lx * 256 + c8);
            *(f16x8*)(Ot + (wx * 8 + lx) * OT_S + c8) = v;
        }
    }
    __syncthreads();

    f32x4 oa[2][4];
    {
        const f32x4 z = {0.f, 0.f, 0.f, 0.f};
        #pragma unroll
        for (int mt = 0; mt < 2; ++mt)
            #pragma unroll
            for (int nt = 0; nt < 4; ++nt) oa[mt][nt] = z;
    }
    #pragma unroll
    for (int kt = 0; kt < 8; ++kt) {
        f16x8 wf[2], of[4];
        #pragma unroll
        for (int mt = 0; mt < 2; ++mt)
            wf[mt] = *(const f16x8*)(wo16k + kt * 8192 + (w * 32 + mt * 16 + m) * 32 + lg * 8);
        #pragma unroll
        for (int nt = 0; nt < 4; ++nt)
            of[nt] = *(const f16x8*)(Ot + (nt * 16 + m) * OT_S + kt * 32 + lg * 8);
        #pragma unroll
        for (int mt = 0; mt < 2; ++mt)
            #pragma unroll
            for (int nt = 0; nt < 4; ++nt)
                oa[mt][nt] = __builtin_amdgcn_mfma_f32_16x16x32_f16(wf[mt], of[nt], oa[mt][nt], 0, 0, 0);
    }
    // write out[b][oc][y][px]: 16 consecutive px per (oc) -> 64B segments
    float* ob = out + (size_t)b * 1048576 + y * 64;
    #pragma unroll
    for (int mt = 0; mt < 2; ++mt)
        #pragma unroll
        for (int nt = 0; nt < 4; ++nt) {
            int px = nt * 16 + m;
            #pragma unroll
            for (int r = 0; r < 4; ++r) {
                int oc = w * 32 + mt * 16 + lg * 4 + r;
                ob[(size_t)oc * 4096 + px] = oa[mt][nt][r] + b_out[oc];
            }
        }
}

extern "C" void kernel_launch(void* const* d_in, const int* in_sizes, int n_in,
                              void* d_out, int out_size, void* d_ws, size_t ws_size,
                              hipStream_t stream) {
    const float* x      = (const float*)d_in[0];
    const float* w_proj = (const float*)d_in[1];
    const float* pos    = (const float*)d_in[2];
    const float* w_out  = (const float*)d_in[3];
    const float* b_out  = (const float*)d_in[4];
    float* out = (float*)d_out;

    // d_ws: [0,32M) x_tw ; +32M w16k (384K) ; wo16k (128K) ; Ows (32M)
    u16* xtw   = (u16*)d_ws;
    u16* w16k  = (u16*)((char*)d_ws + 33554432);
    u16* wo16k = (u16*)((char*)d_ws + 33554432 + 393216);
    u16* Ows   = (u16*)((char*)d_ws + 33554432 + 393216 + 131072);

    prep<<<1536, 512, 0, stream>>>(x, w_proj, w_out, xtw, w16k, wo16k);
    lsa_qkv_attn_xt<<<dim3(128, 16), 512, 0, stream>>>(xtw, w16k, pos, Ows);
    lsa_outproj_row<<<dim3(64, 16), 512, 0, stream>>>(Ows, wo16k, b_out, out);
}

// Round 15
// 88.602 us; speedup vs baseline: 1.0591x; 1.0591x over previous
//
#include <hip/hip_runtime.h>

// LocalSelfAttention2d  B=16,C=256,H=W=64,P=8,HEADS=8,D=32
// Round 15: R13 base (R14 reverted — regressed) + in-register P for PV.
//  MFMA contraction needs only A/B agreement on (lg,elem)->k mapping.
//  After st=mfma(kf,qf), lane holds S[q=m][k=kt*16+lg*4+r]. Choose PV mapping
//  k(lg,v) = (2ks+(v>>2))*16 + lg*4 + (v&3):
//   - pf = in-lane repack of st (cvt_pkrtz only) -> P never touches LDS
//   - vf = two b64 LDS reads per dt (same Vt layout), elements match mapping
//   - P-overlay barrier removed (no phase-4 LDS writes exist)
// prep/K2 unchanged (near BW floor).
// MFMA 16x16x32_f16 layouts (verified): A: row=l&15 ; B: col=l&15 ;
//   D: col=l&15 (B-index), row=(l>>4)*4+r (A-index).

typedef _Float16 f16x8 __attribute__((ext_vector_type(8)));
typedef _Float16 f16x4v __attribute__((ext_vector_type(4)));
typedef float    f32x4 __attribute__((ext_vector_type(4)));
typedef unsigned short u16;
typedef unsigned int   u32;
typedef unsigned long long u64;

#define SCALE 0.17677669529663687f  // 1/sqrt(32)
#define QK_S  40    // Q/K [64 pix][40 d]
#define VT_S  72    // V  [32 d][72 k]
#define PB_S  40    // (unused for P now; kept for layout docs)
#define LT_S  264   // transpose staging stride
#define XW_S  264   // x-window LDS stride (528B rows, 2-way banks)
#define OT_S  264   // K2 row-tile stride

__device__ __forceinline__ u16 f2hu(float f) {
    _Float16 h = (_Float16)f; return __builtin_bit_cast(u16, h);
}
__device__ __forceinline__ u64 pack4h(f32x4 v) {
    u32 lo = __builtin_bit_cast(u32, __builtin_amdgcn_cvt_pkrtz(v[0], v[1]));
    u32 hi = __builtin_bit_cast(u32, __builtin_amdgcn_cvt_pkrtz(v[2], v[3]));
    return ((u64)hi << 32) | (u64)lo;
}
__device__ __forceinline__ f16x8 cat44(f16x4v a, f16x4v b) {
    return __builtin_shufflevector(a, b, 0, 1, 2, 3, 4, 5, 6, 7);
}

// ---------------- prep: fused weight-convert + x transpose ----------------
__global__ __launch_bounds__(512)
void prep(const float* __restrict__ x, const float* __restrict__ wp,
          const float* __restrict__ wo, u16* __restrict__ xtw,
          u16* __restrict__ w16k, u16* __restrict__ wo16k)
{
    __shared__ u16 Lt[64 * LT_S];
    const int bid = blockIdx.x;
    const int tid = threadIdx.x;
    if (bid < 1024) {
        const int y = bid & 63, b = bid >> 6;
        const int yq = y >> 3, py = y & 7;
        const float* xb = x + ((size_t)b * 256) * 4096 + y * 64;
        #pragma unroll
        for (int i = 0; i < 8; ++i) {
            int idx = tid + i * 512;            // 4096 float4s
            int c = idx >> 4, w4 = (idx & 15) << 2;
            float4 v = *(const float4*)(xb + (size_t)c * 4096 + w4);
            float vv[4] = {v.x, v.y, v.z, v.w};
            #pragma unroll
            for (int j = 0; j < 4; ++j) {
                int w = w4 + j;
                Lt[w * LT_S + (c ^ (((w >> 2) & 7) << 3))] = f2hu(vv[j]);
            }
        }
        __syncthreads();
        u16* dst = xtw + (size_t)(b * 64 + yq * 8) * 16384;   // window-row base
        #pragma unroll
        for (int i = 0; i < 4; ++i) {
            int idx = tid + i * 512;            // 2048 f16x8 stores
            int w = idx >> 5, c8 = (idx & 31) << 3;
            f16x8 v = *(const f16x8*)(&Lt[w * LT_S + (c8 ^ (((w >> 2) & 7) << 3))]);
            *(f16x8*)(dst + (w >> 3) * 16384 + (py * 8 + (w & 7)) * 256 + c8) = v;
        }
    } else {
        int idx = (bid - 1024) * 512 + tid;     // 0..262143
        if (idx < 196608) {
            int hq = idx / 98304, o = idx - hq * 98304;
            int kt = o / 12288, o2 = o - kt * 12288;
            int lr = o2 >> 5, cc = o2 & 31;
            int s = lr >> 7, hh = (lr >> 5) & 3, d = lr & 31;
            w16k[idx] = f2hu(wp[(size_t)(s * 256 + (hq * 4 + hh) * 32 + d) * 256 + kt * 32 + cc]);
        } else {
            int j = idx - 196608;               // 0..65535
            int kt = j >> 13, o2 = j & 8191;
            int row = o2 >> 5, cc = o2 & 31;
            wo16k[j] = f2hu(wo[(size_t)row * 256 + kt * 32 + cc]);
        }
    }
}

// ---------------- K1: QKV projection + windowed attention ----------------
__global__ __launch_bounds__(512, 4)
void lsa_qkv_attn_xt(const u16* __restrict__ xtw, const u16* __restrict__ w16k,
                     const float* __restrict__ position, u16* __restrict__ Ows)
{
    // U overlay: phase 1-2: XwL[64][264] = 16896 u16
    //            phase 3-4: Qb 10240 | Kb 10240 | Vt 9216 = 29696 u16
    __shared__ u16 U[29696];        // 59392 B
    __shared__ float POSL[1024];    // 4096 B: this block's hq-half (4 heads)
    u16* XwL = U;                   // [64][264]
    u16* Qb  = U;                   // [4][64][40]
    u16* Kb  = U + 10240;
    u16* Vt  = U + 20480;           // [4][32][72]

    const int tid = threadIdx.x;
    const int hq = blockIdx.x & 1, win = blockIdx.x >> 1, b = blockIdx.y;
    const int w = tid >> 6, m = tid & 15, lg = (tid >> 4) & 3;

    // stage position half + x window (shared operands)
    *(float2*)(&POSL[tid * 2]) = *(const float2*)(position + hq * 1024 + tid * 2);
    {
        const u16* xwin = xtw + (size_t)(b * 64 + win) * 16384;
        #pragma unroll
        for (int i = 0; i < 4; ++i) {
            int g = tid + i * 512;              // 2048 16B-chunks
            *(f16x8*)(XwL + (g >> 5) * XW_S + (g & 31) * 8) = *(const f16x8*)(xwin + g * 8);
        }
    }
    __syncthreads();

    // ---- phase 2: QKV GEMM; A (weights) direct global, B (window) from LDS
    f32x4 acc[3][4];
    int isv[3], hhv[3], d0v[3], lr0v[3];
    {
        const f32x4 z = {0.f, 0.f, 0.f, 0.f};
        #pragma unroll
        for (int i = 0; i < 3; ++i) {
            #pragma unroll
            for (int nt = 0; nt < 4; ++nt) acc[i][nt] = z;
            int lr0 = (3 * w + i) * 16;           // local row: s*128 + hh*32 + d
            lr0v[i] = lr0;
            isv[i] = lr0 >> 7; hhv[i] = (lr0 >> 5) & 3; d0v[i] = lr0 & 31;
        }
        const u16* wbase = w16k + (size_t)hq * 98304;
        #pragma unroll
        for (int kt = 0; kt < 8; ++kt) {
            f16x8 af[3], bf[4];
            #pragma unroll
            for (int i = 0; i < 3; ++i)
                af[i] = *(const f16x8*)(wbase + kt * 12288 + (lr0v[i] + m) * 32 + lg * 8);
            #pragma unroll
            for (int nt = 0; nt < 4; ++nt)
                bf[nt] = *(const f16x8*)(XwL + (nt * 16 + m) * XW_S + kt * 32 + lg * 8);
            #pragma unroll
            for (int i = 0; i < 3; ++i)
                #pragma unroll
                for (int nt = 0; nt < 4; ++nt)
                    acc[i][nt] = __builtin_amdgcn_mfma_f32_16x16x32_f16(af[i], bf[nt], acc[i][nt], 0, 0, 0);
        }
    }
    __syncthreads();   // XwL reads done before Q/K/V overlay U

    // ---- phase 3: scatter Q/K/V to per-head LDS (R13-verified)
    {
        #pragma unroll
        for (int i = 0; i < 3; ++i) {
            int i_s = isv[i], hh = hhv[i], d0 = d0v[i];
            #pragma unroll
            for (int nt = 0; nt < 4; ++nt) {
                int pix = nt * 16 + m;
                if (i_s < 2) {
                    u16* base = (i_s == 0) ? Qb : Kb;
                    *(u64*)(base + hh * 64 * QK_S + pix * QK_S + d0 + lg * 4) = pack4h(acc[i][nt]);
                } else {
                    #pragma unroll
                    for (int r = 0; r < 4; ++r)
                        Vt[hh * 32 * VT_S + (d0 + lg * 4 + r) * VT_S + pix] = f2hu(acc[i][nt][r]);
                }
            }
        }
    }
    __syncthreads();

    // ---- phase 4: attention; 2 waves per head; P fully in registers
    {
        const int hh = w >> 1, qh = w & 1;
        const u16* Qh = Qb + hh * 64 * QK_S;
        const u16* Kh = Kb + hh * 64 * QK_S;
        const u16* Vh = Vt + hh * 32 * VT_S;
        const float* posh = &POSL[hh * 256];

        f16x8 kf[4], qf[2];
        #pragma unroll
        for (int kt = 0; kt < 4; ++kt)
            kf[kt] = *(const f16x8*)(Kh + (kt * 16 + m) * QK_S + lg * 8);
        #pragma unroll
        for (int qi = 0; qi < 2; ++qi)
            qf[qi] = *(const f16x8*)(Qh + ((2 * qh + qi) * 16 + m) * QK_S + lg * 8);
        // no barrier needed: phase 4 performs no LDS writes

        const f32x4 z = {0.f, 0.f, 0.f, 0.f};
        f32x4 st[4][2];
        #pragma unroll
        for (int kt = 0; kt < 4; ++kt)
            #pragma unroll
            for (int qi = 0; qi < 2; ++qi)
                st[kt][qi] = __builtin_amdgcn_mfma_f32_16x16x32_f16(kf[kt], qf[qi], z, 0, 0, 0);
        // lane holds S[q=(2qh+qi)*16+m][k=kt*16+lg*4+r]

        float inv[2];
        #pragma unroll
        for (int qi = 0; qi < 2; ++qi) {
            int q = (2 * qh + qi) * 16 + m, qy = q >> 3, qx = q & 7;
            float mx = -1e30f;
            #pragma unroll
            for (int kt = 0; kt < 4; ++kt)
                #pragma unroll
                for (int r = 0; r < 4; ++r) {
                    int k = kt * 16 + lg * 4 + r, ky = k >> 3, kx = k & 7;
                    float t = st[kt][qi][r] * SCALE + posh[(ky - qy + 8) * 16 + (kx - qx + 8)];
                    st[kt][qi][r] = t;
                    mx = fmaxf(mx, t);
                }
            mx = fmaxf(mx, __shfl_xor(mx, 16));
            mx = fmaxf(mx, __shfl_xor(mx, 32));
            float sum = 0.f;
            #pragma unroll
            for (int kt = 0; kt < 4; ++kt)
                #pragma unroll
                for (int r = 0; r < 4; ++r) {
                    float e = __expf(st[kt][qi][r] - mx);
                    st[kt][qi][r] = e; sum += e;
                }
            sum += __shfl_xor(sum, 16);
            sum += __shfl_xor(sum, 32);
            inv[qi] = 1.f / sum;
        }

        // PV with custom k-mapping k(lg,v) = (2ks+(v>>2))*16 + lg*4 + (v&3):
        // pf = in-lane repack of st; vf = two b64 reads matching the mapping.
        f32x4 ot[2][2];
        ot[0][0] = z; ot[0][1] = z; ot[1][0] = z; ot[1][1] = z;
        #pragma unroll
        for (int ks = 0; ks < 2; ++ks) {
            f16x8 pf[2], vf[2];
            #pragma unroll
            for (int qi = 0; qi < 2; ++qi) {
                f16x4v lo = __builtin_bit_cast(f16x4v, pack4h(st[2 * ks + 0][qi] * inv[qi]));
                f16x4v hi = __builtin_bit_cast(f16x4v, pack4h(st[2 * ks + 1][qi] * inv[qi]));
                pf[qi] = cat44(lo, hi);
            }
            #pragma unroll
            for (int dt = 0; dt < 2; ++dt) {
                const u16* vrow = Vh + (dt * 16 + m) * VT_S + lg * 4;
                f16x4v v0 = *(const f16x4v*)(vrow + (2 * ks + 0) * 16);
                f16x4v v1 = *(const f16x4v*)(vrow + (2 * ks + 1) * 16);
                vf[dt] = cat44(v0, v1);
            }
            #pragma unroll
            for (int qi = 0; qi < 2; ++qi)
                #pragma unroll
                for (int dt = 0; dt < 2; ++dt)
                    ot[qi][dt] = __builtin_amdgcn_mfma_f32_16x16x32_f16(pf[qi], vf[dt], ot[qi][dt], 0, 0, 0);
        }

        // O -> Ows [bw][pix][c] fp16 (R13 layout: lane=c-col, regs=q-rows)
        const size_t obase = (size_t)(b * 64 + win) * 16384;
        const int head = hq * 4 + hh;
        #pragma unroll
        for (int qi = 0; qi < 2; ++qi)
            #pragma unroll
            for (int dt = 0; dt < 2; ++dt) {
                int c = head * 32 + dt * 16 + m;
                #pragma unroll
                for (int r = 0; r < 4; ++r) {
                    int q = (2 * qh + qi) * 16 + lg * 4 + r;
                    Ows[obase + q * 256 + c] = f2hu(ot[qi][dt][r]);
                }
            }
    }
}

// -------- K2: out-projection, ROW-major blocks (unchanged R13) --------
__global__ __launch_bounds__(512, 4)
void lsa_outproj_row(const u16* __restrict__ Ows, const u16* __restrict__ wo16k,
                     const float* __restrict__ b_out, float* __restrict__ out)
{
    __shared__ u16 Ot[64 * OT_S];    // 33792 B [64 px][264 c]

    const int tid = threadIdx.x;
    const int y = blockIdx.x, b = blockIdx.y;
    const int yq = y >> 3, py = y & 7;
    const int w = tid >> 6, m = tid & 15, lg = (tid >> 4) & 3;

    {
        const u16* slab = Ows + (size_t)(b * 64 + yq * 8) * 16384 + (py * 8) * 256;
        #pragma unroll
        for (int i = 0; i < 4; ++i) {
            int g = tid + i * 512;              // 2048 16B-chunks
            int wx = g >> 8, gg = g & 255;
            int lx = gg >> 5, c8 = (gg & 31) << 3;
            f16x8 v = *(const f16x8*)(slab + (size_t)wx * 16384 + lx * 256 + c8);
            *(f16x8*)(Ot + (wx * 8 + lx) * OT_S + c8) = v;
        }
    }
    __syncthreads();

    f32x4 oa[2][4];
    {
        const f32x4 z = {0.f, 0.f, 0.f, 0.f};
        #pragma unroll
        for (int mt = 0; mt < 2; ++mt)
            #pragma unroll
            for (int nt = 0; nt < 4; ++nt) oa[mt][nt] = z;
    }
    #pragma unroll
    for (int kt = 0; kt < 8; ++kt) {
        f16x8 wf[2], of[4];
        #pragma unroll
        for (int mt = 0; mt < 2; ++mt)
            wf[mt] = *(const f16x8*)(wo16k + kt * 8192 + (w * 32 + mt * 16 + m) * 32 + lg * 8);
        #pragma unroll
        for (int nt = 0; nt < 4; ++nt)
            of[nt] = *(const f16x8*)(Ot + (nt * 16 + m) * OT_S + kt * 32 + lg * 8);
        #pragma unroll
        for (int mt = 0; mt < 2; ++mt)
            #pragma unroll
            for (int nt = 0; nt < 4; ++nt)
                oa[mt][nt] = __builtin_amdgcn_mfma_f32_16x16x32_f16(wf[mt], of[nt], oa[mt][nt], 0, 0, 0);
    }
    // write out[b][oc][y][px]: 16 consecutive px per (oc) -> 64B segments
    float* ob = out + (size_t)b * 1048576 + y * 64;
    #pragma unroll
    for (int mt = 0; mt < 2; ++mt)
        #pragma unroll
        for (int nt = 0; nt < 4; ++nt) {
            int px = nt * 16 + m;
            #pragma unroll
            for (int r = 0; r < 4; ++r) {
                int oc = w * 32 + mt * 16 + lg * 4 + r;
                ob[(size_t)oc * 4096 + px] = oa[mt][nt][r] + b_out[oc];
            }
        }
}

extern "C" void kernel_launch(void* const* d_in, const int* in_sizes, int n_in,
                              void* d_out, int out_size, void* d_ws, size_t ws_size,
                              hipStream_t stream) {
    const float* x      = (const float*)d_in[0];
    const float* w_proj = (const float*)d_in[1];
    const float* pos    = (const float*)d_in[2];
    const float* w_out  = (const float*)d_in[3];
    const float* b_out  = (const float*)d_in[4];
    float* out = (float*)d_out;

    // d_ws: [0,32M) x_tw ; +32M w16k (384K) ; wo16k (128K) ; Ows (32M)
    u16* xtw   = (u16*)d_ws;
    u16* w16k  = (u16*)((char*)d_ws + 33554432);
    u16* wo16k = (u16*)((char*)d_ws + 33554432 + 393216);
    u16* Ows   = (u16*)((char*)d_ws + 33554432 + 393216 + 131072);

    prep<<<1536, 512, 0, stream>>>(x, w_proj, w_out, xtw, w16k, wo16k);
    lsa_qkv_attn_xt<<<dim3(128, 16), 512, 0, stream>>>(xtw, w16k, pos, Ows);
    lsa_outproj_row<<<dim3(64, 16), 512, 0, stream>>>(Ows, wo16k, b_out, out);
}